// Round 8
// baseline (176.865 us; speedup 1.0000x reference)
//
#include <hip/hip_runtime.h>

#define D_DIRS 4
#define BB 2
#define CC 96
#define LL 4096
#define PP 192
#define TWOP 384
#define NN 16
#define DTR 6
#define NPROJ 38
#define NCH 256
#define CLEN 16
#define SEQT 24576   // 16 n * 8 db * 192 p
#define LOG2E 1.44269504088896340736f

typedef __bf16 bf16x8 __attribute__((ext_vector_type(8)));
typedef float f32x4 __attribute__((ext_vector_type(4)));
typedef float f32x2 __attribute__((ext_vector_type(2)));

__device__ __forceinline__ float fast_softplus(float v) {
    return fmaxf(v, 0.0f) + __logf(1.0f + __expf(-fabsf(v)));
}

// ---------------- weight prep: fp32 -> padded bf16 images ----------------
__global__ void k_prep(const float* __restrict__ W_in, const float* __restrict__ W_x,
                       const float* __restrict__ W_out, __bf16* __restrict__ wbin,
                       __bf16* __restrict__ wbx, __bf16* __restrict__ wbout)
{
    int i = blockIdx.x * 256 + threadIdx.x;
    const int n0 = 4 * 384 * 104, n1 = 4 * 48 * 200, n2 = 4 * 96 * 200;
    if (i < n0) {
        int c = i % 104, jd = i / 104;          // jd = d*384 + j
        wbin[i] = (c < 96) ? (__bf16)W_in[jd * 96 + c] : (__bf16)0.0f;
    } else if (i < n0 + n1) {
        int k = i - n0;
        int c = k % 200, jd = k / 200;          // jd = d*48 + j
        int d = jd / 48, j = jd - d * 48;
        float v = (j < 38 && c < 192) ? W_x[(d * 38 + j) * 192 + c] : 0.0f;
        wbx[k] = (__bf16)v;
    } else if (i < n0 + n1 + n2) {
        int k = i - n0 - n1;
        int c = k % 200, jd = k / 200;          // jd = d*96 + cout
        float v = (c < 192) ? W_out[jd * 192 + c] : 0.0f;
        wbout[k] = (__bf16)v;
    }
}

// ---------------- x1 -> bf16 images: imgH[b][h*64+w][c], imgW[b][w*64+h][c], rows padded to 104 ----------------
__global__ __launch_bounds__(256) void k_img(
    const float* __restrict__ x1, __bf16* __restrict__ imgH, __bf16* __restrict__ imgW)
{
    __shared__ float t[96 * 65];
    const int b = blockIdx.y;
    const int lt = blockIdx.x;        // h
    const int tid = threadIdx.x;
    for (int i = tid; i < 96 * 64; i += 256) {
        int c = i >> 6, lw = i & 63;
        t[c * 65 + lw] = x1[((b * 96 + c) << 12) + (lt << 6) + lw];
    }
    __syncthreads();
    for (int i = tid; i < 64 * 12; i += 256) {
        int lw = i / 12, q = i - lw * 12;
        union { __bf16 h[8]; uint4 u; } pk;
#pragma unroll
        for (int j = 0; j < 8; ++j) pk.h[j] = (__bf16)t[(q * 8 + j) * 65 + lw];
        ((uint4*)(imgH + (long)((b << 12) + (lt << 6) + lw) * 104))[q] = pk.u;
        ((uint4*)(imgW + (long)((b << 12) + (lw << 6) + lt) * 104))[q] = pk.u;
    }
}

// ---------------- input GEMM (MFMA): x-half -> xz_x (f32), z-half -> zb (bf16) ----------------
__global__ __launch_bounds__(256) void k_gemm_in(
    const __bf16* __restrict__ imgH, const __bf16* __restrict__ imgW,
    const __bf16* __restrict__ wbin, float* __restrict__ xz_x, __bf16* __restrict__ zb)
{
    __shared__ __align__(16) __bf16 As[64 * 104];
    __shared__ __align__(16) __bf16 Bs[64 * 104];
    const int db = blockIdx.y;
    const int d = db >> 1, b = db & 1;
    const int t0 = blockIdx.x * 64;
    const int tid = threadIdx.x;
    const __bf16* img = (d < 2 ? imgH : imgW) + (long)b * (LL * 104);

    {
        uint4* adst = (uint4*)As;
        for (int i = tid; i < 832; i += 256) {
            int r = i / 13, q = i - r * 13;
            int l = (d & 1) ? (LL - 1 - (t0 + r)) : (t0 + r);
            adst[i] = ((const uint4*)(img + (long)l * 104))[q];
        }
    }

    const int lane = tid & 63;
    const int w = tid >> 6;
    const int wm = (w >> 1) * 32, wn = (w & 1) * 32;
    const int lr = lane & 15, lk = (lane >> 4) * 8;
    const int orow = (lane >> 4) * 4;

    for (int j0 = 0; j0 < TWOP; j0 += 64) {
        __syncthreads();
        {
            const uint4* bsrc = (const uint4*)(wbin + (long)(d * TWOP + j0) * 104);
            uint4* bdst = (uint4*)Bs;
            for (int i = tid; i < 832; i += 256) bdst[i] = bsrc[i];
        }
        __syncthreads();

        f32x4 acc[2][2] = {{{0.f,0.f,0.f,0.f},{0.f,0.f,0.f,0.f}},
                           {{0.f,0.f,0.f,0.f},{0.f,0.f,0.f,0.f}}};
#pragma unroll
        for (int ks = 0; ks < 96; ks += 32) {
            bf16x8 a0 = *(const bf16x8*)&As[(wm + lr) * 104 + ks + lk];
            bf16x8 a1 = *(const bf16x8*)&As[(wm + 16 + lr) * 104 + ks + lk];
            bf16x8 b0 = *(const bf16x8*)&Bs[(wn + lr) * 104 + ks + lk];
            bf16x8 b1 = *(const bf16x8*)&Bs[(wn + 16 + lr) * 104 + ks + lk];
            acc[0][0] = __builtin_amdgcn_mfma_f32_16x16x32_bf16(a0, b0, acc[0][0], 0, 0, 0);
            acc[0][1] = __builtin_amdgcn_mfma_f32_16x16x32_bf16(a0, b1, acc[0][1], 0, 0, 0);
            acc[1][0] = __builtin_amdgcn_mfma_f32_16x16x32_bf16(a1, b0, acc[1][0], 0, 0, 0);
            acc[1][1] = __builtin_amdgcn_mfma_f32_16x16x32_bf16(a1, b1, acc[1][1], 0, 0, 0);
        }
#pragma unroll
        for (int mi = 0; mi < 2; ++mi)
#pragma unroll
            for (int ni = 0; ni < 2; ++ni) {
                long mbase = (long)(db * LL + t0 + wm + mi * 16 + orow);
                int jcol = j0 + wn + ni * 16 + lr;
                if (j0 < PP) {
#pragma unroll
                    for (int r = 0; r < 4; ++r) xz_x[(mbase + r) * PP + jcol] = acc[mi][ni][r];
                } else {
#pragma unroll
                    for (int r = 0; r < 4; ++r) zb[(mbase + r) * PP + jcol - PP] = (__bf16)acc[mi][ni][r];
                }
            }
    }
}

// ---------------- depthwise causal conv + bias + SiLU -> padded bf16 image [m][200] ----------------
__global__ __launch_bounds__(192) void k_conv(
    const float* __restrict__ xz_x, const float* __restrict__ conv_w,
    const float* __restrict__ conv_b, __bf16* __restrict__ xb16)
{
    __shared__ float xs[67 * 192];
    const int db = blockIdx.y;
    const int t0 = blockIdx.x * 64;
    const int d = db >> 1;
    const int m0 = db * LL + t0;
    const int tid = threadIdx.x;

    const float4* src = (const float4*)(xz_x + ((long)m0 - 3) * PP);
    for (int i = tid; i < 67 * 48; i += 192) {
        float4 v;
        if (t0 == 0 && i < 144) v = make_float4(0.f, 0.f, 0.f, 0.f);
        else v = src[i];
        ((float4*)xs)[i] = v;
    }

    const int p = tid;
    const float* wp = conv_w + (d * PP + p) * 4;
    float w0 = wp[0], w1 = wp[1], w2 = wp[2], w3 = wp[3];
    float bias = conv_b[d * PP + p];
    __syncthreads();

    for (int t = 0; t < 64; ++t) {
        float acc = bias + w0 * xs[t * PP + p] + w1 * xs[(t + 1) * PP + p]
                         + w2 * xs[(t + 2) * PP + p] + w3 * xs[(t + 3) * PP + p];
        float s = acc / (1.0f + __expf(-acc));
        xb16[(long)(m0 + t) * 200 + p] = (__bf16)s;
    }
}

// ---------------- proj GEMM (MFMA): proj[m][j] = sum_k xb16[m][k]*W_x[d][j][k], J=38 ----------------
__global__ __launch_bounds__(256) void k_gemm_proj(
    const __bf16* __restrict__ xb16, const __bf16* __restrict__ wbx, float* __restrict__ proj)
{
    __shared__ __align__(16) __bf16 As[64 * 200];
    __shared__ __align__(16) __bf16 Bs[48 * 200];
    const int m0 = blockIdx.x * 64;
    const int d = m0 >> 13;
    const int tid = threadIdx.x;

    for (int i = tid; i < 1600; i += 256) {
        int r = i / 25, q = i - r * 25;
        ((uint4*)As)[i] = ((const uint4*)(xb16 + (long)(m0 + r) * 200))[q];
    }
    {
        const uint4* bsrc = (const uint4*)(wbx + (long)d * 48 * 200);
        uint4* bdst = (uint4*)Bs;
        for (int i = tid; i < 1200; i += 256) bdst[i] = bsrc[i];
    }
    __syncthreads();

    const int lane = tid & 63;
    const int w = tid >> 6;
    const int lr = lane & 15, lk = (lane >> 4) * 8;
    const int orow = (lane >> 4) * 4;

    f32x4 acc[3] = {{0.f,0.f,0.f,0.f},{0.f,0.f,0.f,0.f},{0.f,0.f,0.f,0.f}};
#pragma unroll
    for (int ks = 0; ks < 192; ks += 32) {
        bf16x8 a = *(const bf16x8*)&As[(w * 16 + lr) * 200 + ks + lk];
#pragma unroll
        for (int ni = 0; ni < 3; ++ni) {
            bf16x8 bfr = *(const bf16x8*)&Bs[(ni * 16 + lr) * 200 + ks + lk];
            acc[ni] = __builtin_amdgcn_mfma_f32_16x16x32_bf16(a, bfr, acc[ni], 0, 0, 0);
        }
    }
#pragma unroll
    for (int ni = 0; ni < 3; ++ni) {
        int j = ni * 16 + lr;
        if (j < NPROJ) {
#pragma unroll
            for (int r = 0; r < 4; ++r) {
                int m = m0 + w * 16 + orow + r;
                proj[(long)m * NPROJ + j] = acc[ni][r];
            }
        }
    }
}

// ---------------- out GEMM (MFMA): yo[m][c] = sum_p ysb[m][p]*W_out[d][c][p], J=96 ----------------
__global__ __launch_bounds__(256) void k_gemm_out(
    const __bf16* __restrict__ ysb, const __bf16* __restrict__ wbout, float* __restrict__ yo)
{
    __shared__ __align__(16) __bf16 As[64 * 200];
    __shared__ __align__(16) __bf16 Bs[96 * 200];
    const int m0 = blockIdx.x * 64;
    const int d = m0 >> 13;
    const int tid = threadIdx.x;

    for (int i = tid; i < 1600; i += 256) {
        int r = i / 25, q = i - r * 25;
        ((uint4*)As)[i] = ((const uint4*)(ysb + (long)(m0 + r) * 200))[q];
    }
    {
        const uint4* bsrc = (const uint4*)(wbout + (long)d * 96 * 200);
        uint4* bdst = (uint4*)Bs;
        for (int i = tid; i < 2400; i += 256) bdst[i] = bsrc[i];
    }
    __syncthreads();

    const int lane = tid & 63;
    const int w = tid >> 6;
    const int wm = (w >> 1) * 32, wn = (w & 1) * 48;
    const int lr = lane & 15, lk = (lane >> 4) * 8;
    const int orow = (lane >> 4) * 4;

    f32x4 acc[2][3] = {};
#pragma unroll
    for (int ks = 0; ks < 192; ks += 32) {
        bf16x8 a0 = *(const bf16x8*)&As[(wm + lr) * 200 + ks + lk];
        bf16x8 a1 = *(const bf16x8*)&As[(wm + 16 + lr) * 200 + ks + lk];
#pragma unroll
        for (int ni = 0; ni < 3; ++ni) {
            bf16x8 bfr = *(const bf16x8*)&Bs[(wn + ni * 16 + lr) * 200 + ks + lk];
            acc[0][ni] = __builtin_amdgcn_mfma_f32_16x16x32_bf16(a0, bfr, acc[0][ni], 0, 0, 0);
            acc[1][ni] = __builtin_amdgcn_mfma_f32_16x16x32_bf16(a1, bfr, acc[1][ni], 0, 0, 0);
        }
    }
#pragma unroll
    for (int mi = 0; mi < 2; ++mi)
#pragma unroll
        for (int ni = 0; ni < 3; ++ni) {
#pragma unroll
            for (int r = 0; r < 4; ++r) {
                int m = m0 + wm + mi * 16 + orow + r;
                yo[(long)m * CC + wn + ni * 16 + lr] = acc[mi][ni][r];
            }
        }
}

// ---------------- scan pass 1: packed f32x2 states, exp2-folded A ----------------
__global__ __launch_bounds__(192) void k_pass1(
    const __bf16* __restrict__ xb16, const float* __restrict__ proj,
    const float* __restrict__ A_log, const float* __restrict__ W_dt,
    const float* __restrict__ b_dt,
    float* __restrict__ cb_pa, float* __restrict__ cb_h)
{
    __shared__ __align__(16) float pl[CLEN * 40];   // 0..5 dtproj, 8..23 B, 24..39 C
    __shared__ __align__(16) __bf16 xsb[CLEN * 200];
    const int tid = threadIdx.x;      // = p
    const int chunk = blockIdx.x;
    const int db = blockIdx.y;
    const int d = db >> 1;
    const int m0 = db * LL + chunk * CLEN;

    const float* pr = proj + (long)m0 * NPROJ;
    for (int i = tid; i < CLEN * NPROJ; i += 192) {
        int r = i / NPROJ, c = i - r * NPROJ;
        int col = (c < 6) ? c : c + 2;
        pl[r * 40 + col] = pr[i];
    }
    for (int i = tid; i < 400; i += 192) {
        int r = i / 25, q = i - r * 25;
        ((uint4*)xsb)[i] = ((const uint4*)(xb16 + (long)(m0 + r) * 200))[q];
    }

    const int p = tid;
    f32x2 A2[8];   // -exp(A_log) * log2(e), packed pairs
    {
        const float4* al4 = reinterpret_cast<const float4*>(A_log + (d * PP + p) * NN);
#pragma unroll
        for (int q = 0; q < 4; ++q) {
            float4 a = al4[q];
            A2[2*q].x   = -__expf(a.x) * LOG2E; A2[2*q].y   = -__expf(a.y) * LOG2E;
            A2[2*q+1].x = -__expf(a.z) * LOG2E; A2[2*q+1].y = -__expf(a.w) * LOG2E;
        }
    }
    float w[6];
    const float* wd = W_dt + (d * PP + p) * DTR;
#pragma unroll
    for (int r = 0; r < 6; ++r) w[r] = wd[r];
    const float bdt = b_dt[d * PP + p];
    f32x2 hv[8];
#pragma unroll
    for (int q = 0; q < 8; ++q) { hv[q].x = 0.f; hv[q].y = 0.f; }
    float sdt = 0.f;
    __syncthreads();

#pragma unroll
    for (int s = 0; s < CLEN; ++s) {
        const float* row = pl + s * 40;
        float4 d0 = *(const float4*)(row);
        float4 d1 = *(const float4*)(row + 4);
        float v = bdt + d0.x*w[0] + d0.y*w[1] + d0.z*w[2] + d0.w*w[3] + d1.x*w[4] + d1.y*w[5];
        float dtv = fast_softplus(v);
        sdt += dtv;
        float dtx = dtv * (float)xsb[s * 200 + p];
        f32x2 dt2; dt2.x = dtv; dt2.y = dtv;
        f32x2 dx2; dx2.x = dtx; dx2.y = dtx;
        const f32x2* B2 = reinterpret_cast<const f32x2*>(row + 8);
#pragma unroll
        for (int q = 0; q < 8; ++q) {
            f32x2 t = dt2 * A2[q];                 // v_pk_mul_f32
            f32x2 dA; dA.x = exp2f(t.x); dA.y = exp2f(t.y);
            hv[q] = dA * hv[q] + dx2 * B2[q];      // v_pk_mul + v_pk_fma
        }
    }
    const long cbase = (long)chunk * SEQT + db * PP + p;
#pragma unroll
    for (int q = 0; q < 8; ++q) {
        cb_pa[cbase + (2*q)   * 1536] = exp2f(A2[q].x * sdt);
        cb_pa[cbase + (2*q+1) * 1536] = exp2f(A2[q].y * sdt);
        cb_h [cbase + (2*q)   * 1536] = hv[q].x;
        cb_h [cbase + (2*q+1) * 1536] = hv[q].y;
    }
}

// ---------------- serial scan over chunks -> initial states ----------------
__global__ void k_chunkscan(const float* __restrict__ cb_pa, float* __restrict__ cb_h)
{
    int j = blockIdx.x * 256 + threadIdx.x;
    float run = 0.0f;
    for (int c = 0; c < NCH; c += 8) {
        float pa[8], hh[8];
#pragma unroll
        for (int i = 0; i < 8; ++i) {
            long o = (long)(c + i) * SEQT + j;
            pa[i] = cb_pa[o]; hh[i] = cb_h[o];
        }
#pragma unroll
        for (int i = 0; i < 8; ++i) {
            cb_h[(long)(c + i) * SEQT + j] = run;
            run = pa[i] * run + hh[i];
        }
    }
}

// ---------------- scan pass 2: ysb = (sum_n h*C + x*Dp) * silu(z), bf16 padded [m][200] ----------------
__global__ __launch_bounds__(192) void k_pass2(
    const __bf16* __restrict__ xb16, const float* __restrict__ proj,
    const float* __restrict__ A_log, const float* __restrict__ W_dt,
    const float* __restrict__ b_dt, const float* __restrict__ Dp,
    const __bf16* __restrict__ zb, const float* __restrict__ cb_h,
    __bf16* __restrict__ ysb)
{
    __shared__ __align__(16) float pl[CLEN * 40];
    __shared__ __align__(16) __bf16 xsb[CLEN * 200];
    __shared__ __align__(16) __bf16 zs[CLEN * PP];
    const int tid = threadIdx.x;
    const int chunk = blockIdx.x;
    const int db = blockIdx.y;
    const int d = db >> 1;
    const int m0 = db * LL + chunk * CLEN;

    const float* pr = proj + (long)m0 * NPROJ;
    for (int i = tid; i < CLEN * NPROJ; i += 192) {
        int r = i / NPROJ, c = i - r * NPROJ;
        int col = (c < 6) ? c : c + 2;
        pl[r * 40 + col] = pr[i];
    }
    for (int i = tid; i < 400; i += 192) {
        int r = i / 25, q = i - r * 25;
        ((uint4*)xsb)[i] = ((const uint4*)(xb16 + (long)(m0 + r) * 200))[q];
    }
    {
        const uint4* zsrc = reinterpret_cast<const uint4*>(zb + (long)m0 * PP);
        uint4* zdst = reinterpret_cast<uint4*>(zs);
        zdst[tid] = zsrc[tid];
        zdst[tid + 192] = zsrc[tid + 192];
    }

    const int p = tid;
    f32x2 A2[8];
    {
        const float4* al4 = reinterpret_cast<const float4*>(A_log + (d * PP + p) * NN);
#pragma unroll
        for (int q = 0; q < 4; ++q) {
            float4 a = al4[q];
            A2[2*q].x   = -__expf(a.x) * LOG2E; A2[2*q].y   = -__expf(a.y) * LOG2E;
            A2[2*q+1].x = -__expf(a.z) * LOG2E; A2[2*q+1].y = -__expf(a.w) * LOG2E;
        }
    }
    float w[6];
    const float* wd = W_dt + (d * PP + p) * DTR;
#pragma unroll
    for (int r = 0; r < 6; ++r) w[r] = wd[r];
    const float bdt = b_dt[d * PP + p];
    const float Dv = Dp[d * PP + p];

    f32x2 hv[8];
    const long cbase = (long)chunk * SEQT + db * PP + p;
#pragma unroll
    for (int q = 0; q < 8; ++q) {
        hv[q].x = cb_h[cbase + (2*q)   * 1536];
        hv[q].y = cb_h[cbase + (2*q+1) * 1536];
    }
    __syncthreads();

#pragma unroll
    for (int s = 0; s < CLEN; ++s) {
        const float* row = pl + s * 40;
        float4 d0 = *(const float4*)(row);
        float4 d1 = *(const float4*)(row + 4);
        float v = bdt + d0.x*w[0] + d0.y*w[1] + d0.z*w[2] + d0.w*w[3] + d1.x*w[4] + d1.y*w[5];
        float dtv = fast_softplus(v);
        float xvv = (float)xsb[s * 200 + p];
        float dtx = dtv * xvv;
        f32x2 dt2; dt2.x = dtv; dt2.y = dtv;
        f32x2 dx2; dx2.x = dtx; dx2.y = dtx;
        const f32x2* B2 = reinterpret_cast<const f32x2*>(row + 8);
        const f32x2* C2 = reinterpret_cast<const f32x2*>(row + 24);
        f32x2 y2; y2.x = 0.f; y2.y = 0.f;
#pragma unroll
        for (int q = 0; q < 8; ++q) {
            f32x2 t = dt2 * A2[q];
            f32x2 dA; dA.x = exp2f(t.x); dA.y = exp2f(t.y);
            hv[q] = dA * hv[q] + dx2 * B2[q];
            y2 = y2 + hv[q] * C2[q];
        }
        float y = y2.x + y2.y;
        float zvv = (float)zs[s * PP + p];
        ysb[(long)(m0 + s) * 200 + p] = (__bf16)((y + xvv * Dv) * (zvv / (1.0f + __expf(-zvv))));
    }
}

// ---------------- final combine ----------------
__global__ void k_final(const float* __restrict__ x2, const float* __restrict__ yo,
                        float* __restrict__ out)
{
    int idx = blockIdx.x * blockDim.x + threadIdx.x;
    const int total = BB * CC * LL;
    for (; idx < total; idx += gridDim.x * blockDim.x) {
        int w = idx & 63;
        int h = (idx >> 6) & 63;
        int c = (idx >> 12) % CC;
        int b = idx / (CC * LL);
        int lh = (h << 6) | w;
        int lw = (w << 6) | h;
        long m0 = (long)(0 * BB + b) * LL + lh;
        long m1 = (long)(1 * BB + b) * LL + (LL - 1 - lh);
        long m2 = (long)(2 * BB + b) * LL + lw;
        long m3 = (long)(3 * BB + b) * LL + (LL - 1 - lw);
        out[idx] = x2[idx] + yo[m0 * CC + c] + yo[m1 * CC + c] + yo[m2 * CC + c] + yo[m3 * CC + c];
    }
}

extern "C" void kernel_launch(void* const* d_in, const int* in_sizes, int n_in,
                              void* d_out, int out_size, void* d_ws, size_t ws_size,
                              hipStream_t stream)
{
    const float* x1     = (const float*)d_in[0];
    const float* x2     = (const float*)d_in[1];
    const float* W_in   = (const float*)d_in[2];
    const float* conv_w = (const float*)d_in[3];
    const float* conv_b = (const float*)d_in[4];
    const float* W_x    = (const float*)d_in[5];
    const float* W_dt   = (const float*)d_in[6];
    const float* b_dt   = (const float*)d_in[7];
    const float* A_log  = (const float*)d_in[8];
    const float* Dp     = (const float*)d_in[9];
    const float* W_out  = (const float*)d_in[10];
    float* out = (float*)d_out;
    float* ws  = (float*)d_ws;

    // workspace (float offsets), total ~27.53M f = 110.1 MB
    float*  xz_x  = ws;                          // 6,291,456  (ysb aliases after conv)
    __bf16* zb    = (__bf16*)(ws + 6291456);     // 3,145,728 f
    __bf16* xb16  = (__bf16*)(ws + 9437184);     // 3,276,800 f
    float*  proj  = ws + 12713984;               // 1,245,184
    float*  cb_pa = ws + 13959168;               // 6,291,456  (yo aliases after chunkscan)
    float*  cb_h  = ws + 20250624;               // 6,291,456
    __bf16* imgH  = (__bf16*)(ws + 26542080);    // 425,984 f
    __bf16* imgW  = (__bf16*)(ws + 26968064);    // 425,984 f
    __bf16* wbin  = (__bf16*)(ws + 27394048);    // 79,872 f
    __bf16* wbx   = (__bf16*)(ws + 27473920);    // 19,200 f
    __bf16* wbout = (__bf16*)(ws + 27493120);    // 38,400 f
    __bf16* ysb = (__bf16*)xz_x;   // xz_x dead after k_conv
    float*  yo  = cb_pa;           // cb_pa dead after k_chunkscan

    k_prep<<<dim3(1074), 256, 0, stream>>>(W_in, W_x, W_out, wbin, wbx, wbout);
    k_img<<<dim3(64, 2), 256, 0, stream>>>(x1, imgH, imgW);
    k_gemm_in<<<dim3(64, 8), 256, 0, stream>>>(imgH, imgW, wbin, xz_x, zb);
    k_conv<<<dim3(64, 8), 192, 0, stream>>>(xz_x, conv_w, conv_b, xb16);
    k_gemm_proj<<<dim3(512), 256, 0, stream>>>(xb16, wbx, proj);
    k_pass1<<<dim3(NCH, 8), 192, 0, stream>>>(xb16, proj, A_log, W_dt, b_dt, cb_pa, cb_h);
    k_chunkscan<<<dim3(SEQT / 256), 256, 0, stream>>>(cb_pa, cb_h);
    k_pass2<<<dim3(NCH, 8), 192, 0, stream>>>(xb16, proj, A_log, W_dt, b_dt, Dp, zb, cb_h, ysb);
    k_gemm_out<<<dim3(512), 256, 0, stream>>>(ysb, wbout, yo);
    k_final<<<dim3(3072), 256, 0, stream>>>(x2, yo, out);
}